// Round 8
// baseline (230.756 us; speedup 1.0000x reference)
//
#include <hip/hip_runtime.h>
#include <cstddef>

typedef __fp16 f16x8 __attribute__((ext_vector_type(8)));
typedef float f32x4 __attribute__((ext_vector_type(4)));
typedef unsigned int uint32;
typedef unsigned short ushort;

constexpr int S = 64, MSG = 32, CH = 73;

// frag-linear f16 weight tiles in ws. One tile = 16 cols x 32 k = 64 lanes x 8 f16.
constexpr int FC1_OFF = 0;          // 12 tiles (t0..2 x f0..3)  K=96 (80 real + bias@80)
constexpr int ATT_OFF = 12 * 512;   // 6 tiles  (t0..2 x f0..1)  K=96 (73 real + bias@73)
constexpr int FC2_OFF = 18 * 512;   // 12 tiles (t0..2 x f0..3)  K=96 exact (bias separate)
constexpr int FC3_OFF = 30 * 512;   // 4 tiles  (t0..1 x f0..1)  K=64 exact (bias separate)
constexpr int WS_ELEMS = 34 * 512;  // 17408 ushort = 34816 B

__global__ void prep_pack(const float* __restrict__ W1, const float* __restrict__ b1,
                          const float* __restrict__ Wa, const float* __restrict__ ba,
                          const float* __restrict__ W2, const float* __restrict__ W3,
                          ushort* __restrict__ wsf) {
  int idx = blockIdx.x * 256 + threadIdx.x;
  if (idx >= WS_ELEMS) return;
  int tile = idx >> 9;
  int lane = (idx >> 3) & 63;
  int e = idx & 7;
  int jloc = lane & 15;
  int kloc = ((lane >> 4) << 3) + e;  // B-frag: lane holds B[k][col=lane&15], k=(lane>>4)*8+e
  float v = 0.f;
  if (tile < 12) {                       // W1 [64][80]
    int t = tile >> 2, f = tile & 3;
    int j = f * 16 + jloc, k = t * 32 + kloc;
    v = (k < 80) ? W1[j * 80 + k] : (k == 80 ? b1[j] : 0.f);
  } else if (tile < 18) {                // Wa [32][73]
    int q = tile - 12, t = q >> 1, f = q & 1;
    int j = f * 16 + jloc, k = t * 32 + kloc;
    v = (k < 73) ? Wa[j * 73 + k] : (k == 73 ? ba[j] : 0.f);
  } else if (tile < 30) {                // W2 [64][96]
    int q = tile - 18, t = q >> 2, f = q & 3;
    int j = f * 16 + jloc, k = t * 32 + kloc;
    v = W2[j * 96 + k];
  } else {                               // W3 [32][64]
    int q = tile - 30, t = q >> 1, f = q & 1;
    int j = f * 16 + jloc, k = t * 32 + kloc;
    v = W3[j * 64 + k];
  }
  union { __fp16 h; ushort s; } cv;
  cv.h = (__fp16)v;
  wsf[idx] = cv.s;
}

__device__ __forceinline__ f32x4 mf(f16x8 a, f16x8 b, f32x4 c) {
  return __builtin_amdgcn_mfma_f32_16x16x32_f16(a, b, c, 0, 0, 0);
}
__device__ __forceinline__ uint32 pku(float a, float b) {
  auto r = __builtin_amdgcn_cvt_pkrtz(a, b);
  union { decltype(r) f; uint32 u; } v; v.f = r; return v.u;
}
__device__ __forceinline__ f16x8 packA(const float* f) {
  union { uint32 u[4]; f16x8 h; } r;
  r.u[0] = pku(f[0], f[1]); r.u[1] = pku(f[2], f[3]);
  r.u[2] = pku(f[4], f[5]); r.u[3] = pku(f[6], f[7]);
  return r.h;
}
__device__ __forceinline__ f16x8 packA2(float4 a, float4 b) {
  union { uint32 u[4]; f16x8 h; } r;
  r.u[0] = pku(a.x, a.y); r.u[1] = pku(a.z, a.w);
  r.u[2] = pku(b.x, b.y); r.u[3] = pku(b.z, b.w);
  return r.h;
}
__device__ __forceinline__ float fast_tanh(float v) {
  v = fminf(15.f, fmaxf(-15.f, v));
  float t = __expf(2.f * v);
  return (t - 1.f) * __builtin_amdgcn_rcpf(t + 1.f);
}

constexpr int HT_LD = 104;  // f16 stride; 208 B (16B-aligned rows)
constexpr int H2_LD = 72;   // f16 stride; 144 B
// per-block smem: hbuf 4w x 3328 B = 13312; then per-wave union region 4672 B
// (csb during attention | h2buf after fc2) x 4w = 18688. total 32000 B.
constexpr int HBUF_B = 3328;
constexpr int UNION_OFF = 13312;
constexpr int UNION_B = 4672;
constexpr int SMEM_B = 32000;

__launch_bounds__(256)
__global__ void critic_mfma_kernel(
    const float* __restrict__ x, const float* __restrict__ u,
    const float* __restrict__ cs, const float* __restrict__ m,
    const float* __restrict__ b2, const float* __restrict__ b3,
    const ushort* __restrict__ wsf, float* __restrict__ out, int n) {
  __shared__ __attribute__((aligned(16))) unsigned char smem[SMEM_B];

  const int wave = threadIdx.x >> 6;
  const int lane = threadIdx.x & 63;
  const int lm = lane & 15;
  const int lq = lane >> 4;

  const int tiles = n >> 4;              // 16-row tiles
  const int wslots = gridDim.x * 4;      // wave slots in grid
  const int tbase = blockIdx.x * 4 + wave;
  if (tbase >= tiles) return;            // no barriers anywhere -> safe

  __fp16* __restrict__ ht = reinterpret_cast<__fp16*>(smem + wave * HBUF_B);
  float* __restrict__ csw = reinterpret_cast<float*>(smem + UNION_OFF + wave * UNION_B);
  __fp16* __restrict__ h2t = reinterpret_cast<__fp16*>(smem + UNION_OFF + wave * UNION_B);

  auto ldB = [&](int off_tile) -> f16x8 {
    return *reinterpret_cast<const f16x8*>(wsf + off_tile + lane * 8);
  };

  f16x8 wa[6];
#pragma unroll
  for (int i = 0; i < 6; ++i) wa[i] = ldB(ATT_OFF + i * 512);

  // cross-iteration staging registers
  float4 csr0, csr1, csr2, csr3, csr4;
  float4 xva, xvb, xvc, xvd, uva, uvb;

  auto issue_cs = [&](int r0, int g) {  // 16 contiguous att-rows = 4672 B, coalesced
    const float4* __restrict__ src =
        reinterpret_cast<const float4*>(cs + (size_t)(r0 * 4 + 16 * g) * CH);
    csr0 = src[lane];       csr1 = src[64 + lane];
    csr2 = src[128 + lane]; csr3 = src[192 + lane];
    if (lane < 36) csr4 = src[256 + lane];
  };
  auto issue_xu = [&](int r0) {
    const float4* __restrict__ xrow4 =
        reinterpret_cast<const float4*>(x + (size_t)(r0 + lm) * S);
    xva = xrow4[2 * lq]; xvb = xrow4[2 * lq + 1];
    xvc = xrow4[8 + 2 * lq]; xvd = xrow4[9 + 2 * lq];
    const int uq = (lq < 2) ? lq : 0;  // clamp: lanes lq>=2 don't use u
    const float4* __restrict__ urow4 =
        reinterpret_cast<const float4*>(u + (size_t)(r0 + lm) * 16);
    uva = urow4[2 * uq]; uvb = urow4[2 * uq + 1];
  };

  // prologue for first tile
  issue_cs(tbase << 4, 0);
  issue_xu(tbase << 4);

  for (int t = 0; t < 2; ++t) {
    const int tile = tbase + t * wslots;
    if (tile >= tiles) break;            // wave-uniform
    const int r0 = tile << 4;
    const int ntile = tile + wslots;
    const bool pre_next = (t == 0) && (ntile < tiles);

    // ============ Attention: 4 subtiles, reg-staged pipeline ============
#pragma unroll
    for (int g = 0; g < 4; ++g) {
      // commit staged regs to LDS (DS in-order per wave: prior reads done)
      {
        float4* __restrict__ dst = reinterpret_cast<float4*>(csw);
        dst[lane] = csr0;       dst[64 + lane] = csr1;
        dst[128 + lane] = csr2; dst[192 + lane] = csr3;
        if (lane < 36) dst[256 + lane] = csr4;
      }
      // prefetch this g's m scalars FIRST (softmax waits only on these)
      float mr[8];
      {
        const float* __restrict__ mrow = m + (size_t)(r0 + 4 * g + lq) * 128;
#pragma unroll
        for (int c = 0; c < 4; ++c) {
          mr[c * 2 + 0] = mrow[c * 32 + lm];
          mr[c * 2 + 1] = mrow[c * 32 + lm + 16];
        }
      }
      // then issue next chunk's loads (this tile g+1, or NEXT TILE's g0)
      if (g < 3) issue_cs(r0, g + 1);
      else if (pre_next) issue_cs(ntile << 4, 0);

      // A-fragments from LDS (wave-private; lgkmcnt orders write->read)
      const float* __restrict__ crow = csw + lm * CH;
      f32x4 zac[2] = {{0.f, 0.f, 0.f, 0.f}, {0.f, 0.f, 0.f, 0.f}};
#pragma unroll
      for (int tt = 0; tt < 3; ++tt) {
        float f[8];
        const int kbase = tt * 32 + lq * 8;
#pragma unroll
        for (int e = 0; e < 8; ++e) {
          int k = kbase + e;
          f[e] = (k < 73) ? crow[k] : (k == 73 ? 1.f : 0.f);
        }
        f16x8 af = packA(f);
        zac[0] = mf(af, wa[tt * 2 + 0], zac[0]);
        zac[1] = mf(af, wa[tt * 2 + 1], zac[1]);
      }
      // D rows: row=4*lq+reg -> b = r0+4g+lq, c = reg; softmax lane-local
#pragma unroll
      for (int f = 0; f < 2; ++f) {
        const int j = lm + 16 * f;
        float e0 = __expf(zac[f][0]);
        float e1 = __expf(zac[f][1]);
        float e2 = __expf(zac[f][2]);
        float e3 = __expf(zac[f][3]);
        float den = (e0 + e1) + (e2 + e3);
        float num = fmaf(mr[0 * 2 + f], e0,
                    fmaf(mr[1 * 2 + f], e1,
                    fmaf(mr[2 * 2 + f], e2, mr[3 * 2 + f] * e3)));
        float mg = num * __builtin_amdgcn_rcpf(den);
        ht[(4 * g + lq) * HT_LD + 64 + j] = (__fp16)fast_tanh(mg);
      }
    }

    // ============ fc1: cat(x,u,1) [16x96] @ W1T ============
    f32x4 hac[4] = {{0.f,0.f,0.f,0.f},{0.f,0.f,0.f,0.f},{0.f,0.f,0.f,0.f},{0.f,0.f,0.f,0.f}};
    {
      f16x8 a0 = packA2(xva, xvb);
      f16x8 a1 = packA2(xvc, xvd);
      // t = 2: k = 64..95 -> u part (lq 0,1) + bias-one (k==80) + zeros
      float f[8];
      float uf[8] = {uva.x, uva.y, uva.z, uva.w, uvb.x, uvb.y, uvb.z, uvb.w};
#pragma unroll
      for (int e = 0; e < 8; ++e) {
        int k = 64 + lq * 8 + e;
        f[e] = (k < 80) ? ((lq < 2) ? uf[e] : 0.f) : (k == 80 ? 1.f : 0.f);
      }
      f16x8 a2f = packA(f);
      // x/u regs consumed -> issue next tile's x/u now (hidden under fc1..fc3)
      if (pre_next) issue_xu(ntile << 4);
#pragma unroll
      for (int fi = 0; fi < 4; ++fi) hac[fi] = mf(a0, ldB(FC1_OFF + fi * 512), hac[fi]);
#pragma unroll
      for (int fi = 0; fi < 4; ++fi) hac[fi] = mf(a1, ldB(FC1_OFF + (4 + fi) * 512), hac[fi]);
#pragma unroll
      for (int fi = 0; fi < 4; ++fi) hac[fi] = mf(a2f, ldB(FC1_OFF + (8 + fi) * 512), hac[fi]);
    }
    // L2 normalize rows of h1, tanh, stash to ht cols 0..63
    {
      float rn[4];
#pragma unroll
      for (int reg = 0; reg < 4; ++reg) {
        float s = hac[0][reg] * hac[0][reg];
        s = fmaf(hac[1][reg], hac[1][reg], s);
        s = fmaf(hac[2][reg], hac[2][reg], s);
        s = fmaf(hac[3][reg], hac[3][reg], s);
        s += __shfl_xor(s, 1);
        s += __shfl_xor(s, 2);
        s += __shfl_xor(s, 4);
        s += __shfl_xor(s, 8);
        rn[reg] = __builtin_amdgcn_rcpf(fmaxf(sqrtf(s), 1e-12f));
      }
#pragma unroll
      for (int fi = 0; fi < 4; ++fi)
#pragma unroll
        for (int reg = 0; reg < 4; ++reg)
          ht[(4 * lq + reg) * HT_LD + lm + 16 * fi] =
              (__fp16)fast_tanh(hac[fi][reg] * rn[reg]);
    }

    // ============ fc2: [16x96] @ W2T + b2, tanh ============
    {
      f32x4 ac2[4] = {{0.f,0.f,0.f,0.f},{0.f,0.f,0.f,0.f},{0.f,0.f,0.f,0.f},{0.f,0.f,0.f,0.f}};
      f16x8 a2[3];
#pragma unroll
      for (int tt = 0; tt < 3; ++tt)
        a2[tt] = *reinterpret_cast<const f16x8*>(ht + lm * HT_LD + tt * 32 + lq * 8);
#pragma unroll
      for (int tt = 0; tt < 3; ++tt)
#pragma unroll
        for (int fi = 0; fi < 4; ++fi)
          ac2[fi] = mf(a2[tt], ldB(FC2_OFF + (tt * 4 + fi) * 512), ac2[fi]);
      // h2t aliases csw — attention reads complete (DS in-order per wave)
#pragma unroll
      for (int fi = 0; fi < 4; ++fi) {
        float bv = b2[lm + 16 * fi];
#pragma unroll
        for (int reg = 0; reg < 4; ++reg)
          h2t[(4 * lq + reg) * H2_LD + lm + 16 * fi] =
              (__fp16)fast_tanh(ac2[fi][reg] + bv);
      }
    }

    // ============ fc3: [16x64] @ W3T + b3, L2 norm, store ============
    {
      f32x4 o[2] = {{0.f,0.f,0.f,0.f},{0.f,0.f,0.f,0.f}};
      f16x8 a3[2];
#pragma unroll
      for (int tt = 0; tt < 2; ++tt)
        a3[tt] = *reinterpret_cast<const f16x8*>(h2t + lm * H2_LD + tt * 32 + lq * 8);
#pragma unroll
      for (int tt = 0; tt < 2; ++tt)
#pragma unroll
        for (int fi = 0; fi < 2; ++fi)
          o[fi] = mf(a3[tt], ldB(FC3_OFF + (tt * 2 + fi) * 512), o[fi]);
#pragma unroll
      for (int fi = 0; fi < 2; ++fi) {
        float bv = b3[lm + 16 * fi];
#pragma unroll
        for (int reg = 0; reg < 4; ++reg) o[fi][reg] += bv;
      }
      float rn2[4];
#pragma unroll
      for (int reg = 0; reg < 4; ++reg) {
        float s = fmaf(o[0][reg], o[0][reg], o[1][reg] * o[1][reg]);
        s += __shfl_xor(s, 1);
        s += __shfl_xor(s, 2);
        s += __shfl_xor(s, 4);
        s += __shfl_xor(s, 8);
        rn2[reg] = __builtin_amdgcn_rcpf(fmaxf(sqrtf(s), 1e-12f));
      }
#pragma unroll
      for (int fi = 0; fi < 2; ++fi)
#pragma unroll
        for (int reg = 0; reg < 4; ++reg)
          out[(size_t)(r0 + 4 * lq + reg) * MSG + lm + 16 * fi] =
              o[fi][reg] * rn2[reg];
    }
  }
}

extern "C" void kernel_launch(void* const* d_in, const int* in_sizes, int n_in,
                              void* d_out, int out_size, void* d_ws, size_t ws_size,
                              hipStream_t stream) {
  const float* x  = (const float*)d_in[0];
  const float* u  = (const float*)d_in[1];
  const float* cs = (const float*)d_in[2];
  const float* m  = (const float*)d_in[3];
  const float* W1 = (const float*)d_in[4];
  const float* b1 = (const float*)d_in[5];
  const float* W2 = (const float*)d_in[6];
  const float* b2 = (const float*)d_in[7];
  const float* W3 = (const float*)d_in[8];
  const float* b3 = (const float*)d_in[9];
  const float* Wa = (const float*)d_in[10];
  const float* ba = (const float*)d_in[11];
  float* out = (float*)d_out;
  ushort* wsf = (ushort*)d_ws;

  const int n = in_sizes[0] / S;  // batch rows
  const int tiles = (n + 15) / 16;

  hipLaunchKernelGGL(prep_pack, dim3((WS_ELEMS + 255) / 256), dim3(256), 0, stream,
                     W1, b1, Wa, ba, W2, W3, wsf);

  // persistent: each wave handles up to 2 tiles (tbase, tbase + gridDim*4)
  const int blocks = (tiles + 7) / 8;
  hipLaunchKernelGGL(critic_mfma_kernel, dim3(blocks), dim3(256), 0, stream,
                     x, u, cs, m, b2, b3, wsf, out, n);
}